// Round 1
// baseline (821.716 us; speedup 1.0000x reference)
//
#include <hip/hip_runtime.h>

// ---------------------------------------------------------------------------
// QuantizedPermutationNoiseLinear  (B=4, S=2048, IN=4096, OUT=1024, ROUNDS=12)
//
// res = QDQ(T(x+nx)) @ QDQ(Tw(w+wn)).T + bias - x@wn.T - nx@(w+wn).T
//
// Strategy:
//   1) transform kernels: all 12 permute+rotate rounds in LDS (ping-pong),
//      2 vectors/block packed as float2; emits f32 transformed tensor,
//      f16 staging of the correction operands (negated for A side),
//      and global min/max via sortable-uint atomics.
//   2) finalize: scale/zp exactly like reference (round-half-even).
//   3) quant kernels: q = clip(rint(t/s+zp)); store dequantized as f16.
//   4) ONE f16 MFMA GEMM, K = 4096(quant) + 4096(-x) + 4096(-nx) = 12288:
//      out = A_all @ B_all.T + bias   (m97-style 128x128 tile, 16x16x32 MFMA,
//      global_load_lds width=16 staging).
// ---------------------------------------------------------------------------

#define IN_F   4096
#define OUT_F  1024
#define MROWS  8192          // B*S
#define KTOT   12288
#define NROUNDS 12

typedef _Float16 f16;
typedef _Float16 f16x8 __attribute__((ext_vector_type(8)));
typedef _Float16 f16x4 __attribute__((ext_vector_type(4)));
typedef float    f32x4 __attribute__((ext_vector_type(4)));

// ---- workspace layout (bytes) --- total ~377.5 MB -------------------------
#define OFF_XT  (0ull)                                   // 8192*4096*4 = 128 MB
#define OFF_WT  (OFF_XT + (size_t)MROWS * IN_F * 4)      // 1024*4096*4 = 16 MB
#define OFF_A   (OFF_WT + (size_t)OUT_F * IN_F * 4)      // 8192*12288*2 = 192 MB
#define OFF_B   (OFF_A + (size_t)MROWS * KTOT * 2)       // 1024*12288*2 = 24 MB
#define OFF_MM  (OFF_B + (size_t)OUT_F * KTOT * 2)       // 4 u32 + 4 f32

// ---- sortable-uint encoding for float atomic min/max ----------------------
__device__ __forceinline__ unsigned enc_f(float f) {
  unsigned u = __float_as_uint(f);
  return (u & 0x80000000u) ? ~u : (u | 0x80000000u);
}
__device__ __forceinline__ float dec_f(unsigned u) {
  unsigned b = (u & 0x80000000u) ? (u & 0x7fffffffu) : ~u;
  return __uint_as_float(b);
}

__global__ void init_mm_kernel(unsigned* mm) {
  mm[0] = 0xFFFFFFFFu;  // x min (encoded domain)
  mm[1] = 0u;           // x max
  mm[2] = 0xFFFFFFFFu;  // w min
  mm[3] = 0u;           // w max
}

// ---------------------------------------------------------------------------
// Transform: 2 vectors per block, float2-packed, 12 rounds in LDS.
//  IS_W=false: in0=x, in1=noise_x; transform (x+nx) with mats;
//              f16out rows: [.. | -x | -nx]   (A_all, negated)
//  IS_W=true : in0=weight, in1=weight_noise; transform (w+wn) with inv(M)^T;
//              f16out rows: [.. | wn | w+wn]  (B_all)
// ---------------------------------------------------------------------------
template <bool IS_W>
__global__ __launch_bounds__(256) void transform_kernel(
    const float* __restrict__ in0, const float* __restrict__ in1,
    const int* __restrict__ perms, const float* __restrict__ mats,
    float* __restrict__ tout, f16* __restrict__ f16out,
    unsigned* __restrict__ mm, int mmidx) {
  __shared__ float2 buf[2][IN_F];   // exactly 64 KB
  const int t = threadIdx.x;
  const size_t m0 = (size_t)blockIdx.x * 2;

  const float4* r0a = (const float4*)(in0 + m0 * IN_F);
  const float4* r0b = (const float4*)(in1 + m0 * IN_F);
  const float4* r1a = (const float4*)(in0 + (m0 + 1) * IN_F);
  const float4* r1b = (const float4*)(in1 + (m0 + 1) * IN_F);
  f16* f0 = f16out + m0 * KTOT;
  f16* f1 = f16out + (m0 + 1) * KTOT;

#pragma unroll
  for (int j = 0; j < 4; j++) {
    int i4 = j * 256 + t;
    float4 a0 = r0a[i4], b0 = r0b[i4], a1 = r1a[i4], b1 = r1b[i4];
    float4 s0 = make_float4(a0.x + b0.x, a0.y + b0.y, a0.z + b0.z, a0.w + b0.w);
    float4 s1 = make_float4(a1.x + b1.x, a1.y + b1.y, a1.z + b1.z, a1.w + b1.w);
    int c = i4 * 4;
    *(float4*)&buf[0][c]     = make_float4(s0.x, s1.x, s0.y, s1.y);
    *(float4*)&buf[0][c + 2] = make_float4(s0.z, s1.z, s0.w, s1.w);
    f16x4 p0, p1, q0, q1;
    if (IS_W) {
      p0.x=(f16)b0.x; p0.y=(f16)b0.y; p0.z=(f16)b0.z; p0.w=(f16)b0.w;   // wn row m0
      q0.x=(f16)s0.x; q0.y=(f16)s0.y; q0.z=(f16)s0.z; q0.w=(f16)s0.w;   // w~ row m0
      p1.x=(f16)b1.x; p1.y=(f16)b1.y; p1.z=(f16)b1.z; p1.w=(f16)b1.w;
      q1.x=(f16)s1.x; q1.y=(f16)s1.y; q1.z=(f16)s1.z; q1.w=(f16)s1.w;
    } else {
      p0.x=(f16)(-a0.x); p0.y=(f16)(-a0.y); p0.z=(f16)(-a0.z); p0.w=(f16)(-a0.w); // -x
      q0.x=(f16)(-b0.x); q0.y=(f16)(-b0.y); q0.z=(f16)(-b0.z); q0.w=(f16)(-b0.w); // -nx
      p1.x=(f16)(-a1.x); p1.y=(f16)(-a1.y); p1.z=(f16)(-a1.z); p1.w=(f16)(-a1.w);
      q1.x=(f16)(-b1.x); q1.y=(f16)(-b1.y); q1.z=(f16)(-b1.z); q1.w=(f16)(-b1.w);
    }
    *(f16x4*)(f0 + IN_F + c)     = p0;
    *(f16x4*)(f0 + 2 * IN_F + c) = q0;
    *(f16x4*)(f1 + IN_F + c)     = p1;
    *(f16x4*)(f1 + 2 * IN_F + c) = q1;
  }
  __syncthreads();

  int cur = 0;
  for (int r = 0; r < NROUNDS; r++) {
    const int2* prow = (const int2*)(perms + (size_t)r * IN_F);
    const float4* mrow = (const float4*)(mats + (size_t)r * (IN_F / 2) * 4);
#pragma unroll
    for (int i = 0; i < 8; i++) {
      int g = i * 256 + t;              // pair index 0..2047
      int2 p = prow[g];
      float4 m = mrow[g];               // (m00, m01, m10, m11)
      float2 X0 = buf[cur][p.x];
      float2 X1 = buf[cur][p.y];
      float y0x, y0y, y1x, y1y;
      if (IS_W) {
        // inverse-transpose block: [[d,-c],[-b,a]]/det
        float rd = 1.0f / (m.x * m.w - m.y * m.z);
        y0x = (m.w * X0.x - m.z * X1.x) * rd;
        y0y = (m.w * X0.y - m.z * X1.y) * rd;
        y1x = (m.x * X1.x - m.y * X0.x) * rd;
        y1y = (m.x * X1.y - m.y * X0.y) * rd;
      } else {
        y0x = m.x * X0.x + m.y * X1.x;
        y0y = m.x * X0.y + m.y * X1.y;
        y1x = m.z * X0.x + m.w * X1.x;
        y1y = m.z * X0.y + m.w * X1.y;
      }
      *(float4*)&buf[cur ^ 1][2 * g] = make_float4(y0x, y0y, y1x, y1y);
    }
    cur ^= 1;
    __syncthreads();
  }
  // 12 rounds (even) -> result in buf[0]; buf[1] is dead -> reuse as scratch.
  float lmin = 3.4e38f, lmax = -3.4e38f;
  float4* o0 = (float4*)(tout + m0 * IN_F);
  float4* o1 = (float4*)(tout + (m0 + 1) * IN_F);
#pragma unroll
  for (int j = 0; j < 4; j++) {
    int i4 = j * 256 + t;
    int c = i4 * 4;
    float4 q0 = *(float4*)&buf[0][c];       // {v0[c],v1[c],v0[c+1],v1[c+1]}
    float4 q1 = *(float4*)&buf[0][c + 2];
    o0[i4] = make_float4(q0.x, q0.z, q1.x, q1.z);
    o1[i4] = make_float4(q0.y, q0.w, q1.y, q1.w);
    lmin = fminf(lmin, fminf(fminf(q0.x, q0.y), fminf(q0.z, q0.w)));
    lmin = fminf(lmin, fminf(fminf(q1.x, q1.y), fminf(q1.z, q1.w)));
    lmax = fmaxf(lmax, fmaxf(fmaxf(q0.x, q0.y), fmaxf(q0.z, q0.w)));
    lmax = fmaxf(lmax, fmaxf(fmaxf(q1.x, q1.y), fmaxf(q1.z, q1.w)));
  }
#pragma unroll
  for (int off = 32; off > 0; off >>= 1) {
    lmin = fminf(lmin, __shfl_down(lmin, off));
    lmax = fmaxf(lmax, __shfl_down(lmax, off));
  }
  float* red = (float*)&buf[1][0];
  int wid = t >> 6;
  if ((t & 63) == 0) { red[wid * 2] = lmin; red[wid * 2 + 1] = lmax; }
  __syncthreads();
  if (t == 0) {
    float bmin = fminf(fminf(red[0], red[2]), fminf(red[4], red[6]));
    float bmax = fmaxf(fmaxf(red[1], red[3]), fmaxf(red[5], red[7]));
    atomicMin(&mm[mmidx], enc_f(bmin));
    atomicMax(&mm[mmidx + 1], enc_f(bmax));
  }
}

__global__ void finalize_kernel(unsigned* mm) {
  float* sc = (float*)(mm + 4);
  float xlo = dec_f(mm[0]), xhi = dec_f(mm[1]);
  float wlo = dec_f(mm[2]), whi = dec_f(mm[3]);
  float sx = (xhi - xlo) / 255.0f;
  float zx = rintf(-128.0f - xlo / sx);   // jnp.round == half-even == rintf
  float sw = (whi - wlo) / 255.0f;
  float zw = rintf(-128.0f - wlo / sw);
  sc[0] = sx; sc[1] = zx; sc[2] = sw; sc[3] = zw;
}

// quantize->dequantize one 4096-row into f16 at stride KTOT
__global__ __launch_bounds__(256) void quant_kernel(
    const float* __restrict__ src, f16* __restrict__ dst,
    const unsigned* __restrict__ mm, int scoff) {
  const float* sc = (const float*)(mm + 4);
  float s = sc[scoff], zp = sc[scoff + 1];
  int m = blockIdx.x, t = threadIdx.x;
  const float4* srow = (const float4*)(src + (size_t)m * IN_F);
  f16* drow = dst + (size_t)m * KTOT;
#pragma unroll
  for (int j = 0; j < 4; j++) {
    int i4 = j * 256 + t;
    float4 v = srow[i4];
    float q0 = (fminf(fmaxf(rintf(v.x / s + zp), -128.f), 127.f) - zp) * s;
    float q1 = (fminf(fmaxf(rintf(v.y / s + zp), -128.f), 127.f) - zp) * s;
    float q2 = (fminf(fmaxf(rintf(v.z / s + zp), -128.f), 127.f) - zp) * s;
    float q3 = (fminf(fmaxf(rintf(v.w / s + zp), -128.f), 127.f) - zp) * s;
    f16x4 o; o.x = (f16)q0; o.y = (f16)q1; o.z = (f16)q2; o.w = (f16)q3;
    *(f16x4*)(drow + i4 * 4) = o;
  }
}

// ---------------------------------------------------------------------------
// GEMM: out[8192,1024] = A_all[8192,12288] @ B_all[1024,12288]^T + bias
// 128x128 tile, 4 waves (2x2), each wave 4x4 of 16x16x32 f16 MFMA,
// global_load_lds width-16 staging (m97 structure).
// ---------------------------------------------------------------------------
__device__ __forceinline__ void gl2lds16(const void* g, void* l) {
  __builtin_amdgcn_global_load_lds(
      (__attribute__((address_space(1))) void*)g,
      (__attribute__((address_space(3))) void*)l, 16, 0, 0);
}

__global__ __launch_bounds__(256, 2) void gemm_kernel(
    const f16* __restrict__ A, const f16* __restrict__ B,
    const float* __restrict__ bias, float* __restrict__ out) {
  __shared__ f16 As[128 * 32];
  __shared__ f16 Bs[128 * 32];
  const int tid = threadIdx.x;
  const int wave = tid >> 6, lane = tid & 63;
  const int quad = lane >> 4, fr = lane & 15;
  const int bm = blockIdx.x >> 3, bn = blockIdx.x & 7;  // bn fastest: same-bm
  const int wm = (wave & 1) * 64, wn = (wave >> 1) * 64; //  blocks co-schedule

  f32x4 acc[4][4] = {};

  const int l4 = lane >> 2;          // row-within-16 covered by this lane
  const int lc = (lane & 3) * 8;     // f16 col offset (16B chunks)
  const size_t arow = (size_t)(bm * 128 + wave * 16 + l4);
  const size_t brow = (size_t)(bn * 128 + wave * 16 + l4);
  const f16* ag0 = A + arow * KTOT + lc;
  const f16* ag1 = A + (arow + 64) * KTOT + lc;
  const f16* bg0 = B + brow * KTOT + lc;
  const f16* bg1 = B + (brow + 64) * KTOT + lc;
  f16* as0 = As + (wave * 16) * 32;          // wave-uniform LDS bases
  f16* as1 = As + (64 + wave * 16) * 32;
  f16* bs0 = Bs + (wave * 16) * 32;
  f16* bs1 = Bs + (64 + wave * 16) * 32;

  for (int kk = 0; kk < KTOT; kk += 32) {
    gl2lds16(ag0 + kk, as0);
    gl2lds16(ag1 + kk, as1);
    gl2lds16(bg0 + kk, bs0);
    gl2lds16(bg1 + kk, bs1);
    __syncthreads();
    f16x8 af[4], bf[4];
#pragma unroll
    for (int mi = 0; mi < 4; mi++)
      af[mi] = *(const f16x8*)(As + (wm + mi * 16 + fr) * 32 + quad * 8);
#pragma unroll
    for (int ni = 0; ni < 4; ni++)
      bf[ni] = *(const f16x8*)(Bs + (wn + ni * 16 + fr) * 32 + quad * 8);
#pragma unroll
    for (int mi = 0; mi < 4; mi++)
#pragma unroll
      for (int ni = 0; ni < 4; ni++)
        acc[mi][ni] = __builtin_amdgcn_mfma_f32_16x16x32_f16(
            af[mi], bf[ni], acc[mi][ni], 0, 0, 0);
    __syncthreads();
  }

#pragma unroll
  for (int mi = 0; mi < 4; mi++) {
    int gm = bm * 128 + wm + mi * 16 + quad * 4;   // D row = quad*4+reg
#pragma unroll
    for (int ni = 0; ni < 4; ni++) {
      int gn = bn * 128 + wn + ni * 16 + fr;       // D col = lane&15
      float bv = bias[gn];
#pragma unroll
      for (int e = 0; e < 4; e++)
        out[(size_t)(gm + e) * OUT_F + gn] = acc[mi][ni][e] + bv;
    }
  }
}

// ---------------------------------------------------------------------------
extern "C" void kernel_launch(void* const* d_in, const int* in_sizes, int n_in,
                              void* d_out, int out_size, void* d_ws, size_t ws_size,
                              hipStream_t stream) {
  const float* x     = (const float*)d_in[0];
  const float* w     = (const float*)d_in[1];
  const float* bias  = (const float*)d_in[2];
  const float* wn    = (const float*)d_in[3];
  const float* nx    = (const float*)d_in[4];
  const int*   perms = (const int*)d_in[5];
  const float* mats  = (const float*)d_in[6];
  float* out = (float*)d_out;

  char* ws = (char*)d_ws;                       // needs ~377.5 MB
  float* xt   = (float*)(ws + OFF_XT);
  float* wt   = (float*)(ws + OFF_WT);
  f16*   Aall = (f16*)(ws + OFF_A);
  f16*   Ball = (f16*)(ws + OFF_B);
  unsigned* mm = (unsigned*)(ws + OFF_MM);

  init_mm_kernel<<<1, 1, 0, stream>>>(mm);
  transform_kernel<false><<<MROWS / 2, 256, 0, stream>>>(x, nx, perms, mats, xt, Aall, mm, 0);
  transform_kernel<true><<<OUT_F / 2, 256, 0, stream>>>(w, wn, perms, mats, wt, Ball, mm, 2);
  finalize_kernel<<<1, 1, 0, stream>>>(mm);
  quant_kernel<<<MROWS, 256, 0, stream>>>(xt, Aall, mm, 0);
  quant_kernel<<<OUT_F, 256, 0, stream>>>(wt, Ball, mm, 2);
  gemm_kernel<<<(MROWS / 128) * (OUT_F / 128), 256, 0, stream>>>(Aall, Ball, bias, out);
}

// Round 2
// 755.419 us; speedup vs baseline: 1.0878x; 1.0878x over previous
//
#include <hip/hip_runtime.h>

// ---------------------------------------------------------------------------
// QuantizedPermutationNoiseLinear  (B=4, S=2048, IN=4096, OUT=1024, ROUNDS=12)
//
// res = QDQ(T(x+nx)) @ QDQ(Tw(w+wn)).T + bias - x@wn.T - nx@(w+wn).T
//
// R2 changes vs R1:
//  - GEMM block swizzle: bm = blk&63 (XCD = blk%8 = bm%8) so the 8 blocks
//    sharing an A-tile are co-resident on ONE XCD -> A fetched once/XCD.
//  - Transform rounds merged pairwise (12 -> 6 LDS passes) via precomputed
//    4-index/8-coefficient tables (built once per launch, L2-resident).
// ---------------------------------------------------------------------------

#define IN_F   4096
#define OUT_F  1024
#define MROWS  8192          // B*S
#define KTOT   12288
#define NROUNDS 12
#define NPASS  6             // merged rounds

typedef _Float16 f16;
typedef _Float16 f16x8 __attribute__((ext_vector_type(8)));
typedef _Float16 f16x4 __attribute__((ext_vector_type(4)));
typedef float    f32x4 __attribute__((ext_vector_type(4)));

// ---- workspace layout (bytes) --- total ~379 MB ---------------------------
#define OFF_XT  (0ull)                                   // 8192*4096*4 = 128 MB
#define OFF_WT  (OFF_XT + (size_t)MROWS * IN_F * 4)      // 1024*4096*4 = 16 MB
#define OFF_A   (OFF_WT + (size_t)OUT_F * IN_F * 4)      // 8192*12288*2 = 192 MB
#define OFF_B   (OFF_A + (size_t)MROWS * KTOT * 2)       // 1024*12288*2 = 24 MB
#define OFF_MM  (OFF_B + (size_t)OUT_F * KTOT * 2)       // 4 u32 + 4 f32
#define OFF_TIX (OFF_MM + 256)                           // 6*2048*16 = 192 KB
#define OFF_TCX (OFF_TIX + (size_t)NPASS * 2048 * 16)    // 6*2048*32 = 384 KB
#define OFF_TIW (OFF_TCX + (size_t)NPASS * 2048 * 32)
#define OFF_TCW (OFF_TIW + (size_t)NPASS * 2048 * 16)

// ---- sortable-uint encoding for float atomic min/max ----------------------
__device__ __forceinline__ unsigned enc_f(float f) {
  unsigned u = __float_as_uint(f);
  return (u & 0x80000000u) ? ~u : (u | 0x80000000u);
}
__device__ __forceinline__ float dec_f(unsigned u) {
  unsigned b = (u & 0x80000000u) ? (u & 0x7fffffffu) : ~u;
  return __uint_as_float(b);
}

__global__ void init_mm_kernel(unsigned* mm) {
  mm[0] = 0xFFFFFFFFu;  // x min (encoded domain)
  mm[1] = 0u;           // x max
  mm[2] = 0xFFFFFFFFu;  // w min
  mm[3] = 0u;           // w max
}

// ---------------------------------------------------------------------------
// Build merged-round tables. Pass p composes rounds r0=2p, r1=2p+1:
//   y[2g]   = kA . (x[i0], x[i1], x[i2], x[i3])
//   y[2g+1] = kB . (x[i0], x[i1], x[i2], x[i3])
// Forward (x) uses blocks M; weight path uses N = inv(M)^T = [[d,-c],[-b,a]]/det.
// ---------------------------------------------------------------------------
__global__ void build_tables_kernel(const int* __restrict__ perms,
                                    const float* __restrict__ mats,
                                    int4* __restrict__ tIx, float4* __restrict__ tCx,
                                    int4* __restrict__ tIw, float4* __restrict__ tCw) {
  int p = blockIdx.x;  // 0..5
  int r0 = 2 * p, r1 = 2 * p + 1;
  for (int g = threadIdx.x; g < 2048; g += blockDim.x) {
    int q0 = perms[r1 * IN_F + 2 * g], q1 = perms[r1 * IN_F + 2 * g + 1];
    int a0 = q0 >> 1, e0 = q0 & 1, a1 = q1 >> 1, e1 = q1 & 1;
    int4 idx = make_int4(perms[r0 * IN_F + 2 * a0], perms[r0 * IN_F + 2 * a0 + 1],
                         perms[r0 * IN_F + 2 * a1], perms[r0 * IN_F + 2 * a1 + 1]);
    const float* Ma = mats + ((size_t)r0 * 2048 + a0) * 4;  // [a,b,c,d] row-major
    const float* Mb = mats + ((size_t)r0 * 2048 + a1) * 4;
    const float* M1 = mats + ((size_t)r1 * 2048 + g) * 4;
    int o = p * 2048 + g;
    // ---- forward ----
    {
      float c00 = Ma[e0 * 2], c01 = Ma[e0 * 2 + 1];
      float c10 = Mb[e1 * 2], c11 = Mb[e1 * 2 + 1];
      float m00 = M1[0], m01 = M1[1], m10 = M1[2], m11 = M1[3];
      tIx[o] = idx;
      tCx[2 * o]     = make_float4(m00 * c00, m00 * c01, m01 * c10, m01 * c11);
      tCx[2 * o + 1] = make_float4(m10 * c00, m10 * c01, m11 * c10, m11 * c11);
    }
    // ---- inverse-transpose (weight) ----
    {
      float rda = 1.0f / (Ma[0] * Ma[3] - Ma[1] * Ma[2]);
      float rdb = 1.0f / (Mb[0] * Mb[3] - Mb[1] * Mb[2]);
      float rd1 = 1.0f / (M1[0] * M1[3] - M1[1] * M1[2]);
      // N = [[d,-c],[-b,a]]/det ; row e
      float c00 = (e0 == 0 ? Ma[3] : -Ma[1]) * rda;
      float c01 = (e0 == 0 ? -Ma[2] : Ma[0]) * rda;
      float c10 = (e1 == 0 ? Mb[3] : -Mb[1]) * rdb;
      float c11 = (e1 == 0 ? -Mb[2] : Mb[0]) * rdb;
      float m00 = M1[3] * rd1, m01 = -M1[2] * rd1;
      float m10 = -M1[1] * rd1, m11 = M1[0] * rd1;
      tIw[o] = idx;
      tCw[2 * o]     = make_float4(m00 * c00, m00 * c01, m01 * c10, m01 * c11);
      tCw[2 * o + 1] = make_float4(m10 * c00, m10 * c01, m11 * c10, m11 * c11);
    }
  }
}

// ---------------------------------------------------------------------------
// Transform: 2 vectors per block, float2-packed, 6 merged passes in LDS.
//  IS_W=false: in0=x, in1=noise_x; f16out rows: [.. | -x | -nx]  (A_all)
//  IS_W=true : in0=weight, in1=weight_noise; f16out rows: [.. | wn | w+wn]
// ---------------------------------------------------------------------------
template <bool IS_W>
__global__ __launch_bounds__(256) void transform_kernel(
    const float* __restrict__ in0, const float* __restrict__ in1,
    const int4* __restrict__ tI, const float4* __restrict__ tC,
    float* __restrict__ tout, f16* __restrict__ f16out,
    unsigned* __restrict__ mm, int mmidx) {
  __shared__ float2 buf[2][IN_F];   // exactly 64 KB
  const int t = threadIdx.x;
  const size_t m0 = (size_t)blockIdx.x * 2;

  const float4* r0a = (const float4*)(in0 + m0 * IN_F);
  const float4* r0b = (const float4*)(in1 + m0 * IN_F);
  const float4* r1a = (const float4*)(in0 + (m0 + 1) * IN_F);
  const float4* r1b = (const float4*)(in1 + (m0 + 1) * IN_F);
  f16* f0 = f16out + m0 * KTOT;
  f16* f1 = f16out + (m0 + 1) * KTOT;

#pragma unroll
  for (int j = 0; j < 4; j++) {
    int i4 = j * 256 + t;
    float4 a0 = r0a[i4], b0 = r0b[i4], a1 = r1a[i4], b1 = r1b[i4];
    float4 s0 = make_float4(a0.x + b0.x, a0.y + b0.y, a0.z + b0.z, a0.w + b0.w);
    float4 s1 = make_float4(a1.x + b1.x, a1.y + b1.y, a1.z + b1.z, a1.w + b1.w);
    int c = i4 * 4;
    *(float4*)&buf[0][c]     = make_float4(s0.x, s1.x, s0.y, s1.y);
    *(float4*)&buf[0][c + 2] = make_float4(s0.z, s1.z, s0.w, s1.w);
    f16x4 p0, p1, q0, q1;
    if (IS_W) {
      p0.x=(f16)b0.x; p0.y=(f16)b0.y; p0.z=(f16)b0.z; p0.w=(f16)b0.w;   // wn
      q0.x=(f16)s0.x; q0.y=(f16)s0.y; q0.z=(f16)s0.z; q0.w=(f16)s0.w;   // w+wn
      p1.x=(f16)b1.x; p1.y=(f16)b1.y; p1.z=(f16)b1.z; p1.w=(f16)b1.w;
      q1.x=(f16)s1.x; q1.y=(f16)s1.y; q1.z=(f16)s1.z; q1.w=(f16)s1.w;
    } else {
      p0.x=(f16)(-a0.x); p0.y=(f16)(-a0.y); p0.z=(f16)(-a0.z); p0.w=(f16)(-a0.w); // -x
      q0.x=(f16)(-b0.x); q0.y=(f16)(-b0.y); q0.z=(f16)(-b0.z); q0.w=(f16)(-b0.w); // -nx
      p1.x=(f16)(-a1.x); p1.y=(f16)(-a1.y); p1.z=(f16)(-a1.z); p1.w=(f16)(-a1.w);
      q1.x=(f16)(-b1.x); q1.y=(f16)(-b1.y); q1.z=(f16)(-b1.z); q1.w=(f16)(-b1.w);
    }
    *(f16x4*)(f0 + IN_F + c)     = p0;
    *(f16x4*)(f0 + 2 * IN_F + c) = q0;
    *(f16x4*)(f1 + IN_F + c)     = p1;
    *(f16x4*)(f1 + 2 * IN_F + c) = q1;
  }
  __syncthreads();

  int cur = 0;
  for (int pass = 0; pass < NPASS; pass++) {
    const int4* ti = tI + pass * 2048;
    const float4* tc = tC + (size_t)pass * 4096;
#pragma unroll
    for (int i = 0; i < 8; i++) {
      int g = i * 256 + t;              // output pair index 0..2047
      int4 id = ti[g];
      float4 cA = tc[2 * g], cB = tc[2 * g + 1];
      float2 x0 = buf[cur][id.x], x1 = buf[cur][id.y];
      float2 x2 = buf[cur][id.z], x3 = buf[cur][id.w];
      float y0x = cA.x * x0.x + cA.y * x1.x + cA.z * x2.x + cA.w * x3.x;
      float y0y = cA.x * x0.y + cA.y * x1.y + cA.z * x2.y + cA.w * x3.y;
      float y1x = cB.x * x0.x + cB.y * x1.x + cB.z * x2.x + cB.w * x3.x;
      float y1y = cB.x * x0.y + cB.y * x1.y + cB.z * x2.y + cB.w * x3.y;
      *(float4*)&buf[cur ^ 1][2 * g] = make_float4(y0x, y0y, y1x, y1y);
    }
    cur ^= 1;
    __syncthreads();
  }
  // result in buf[0]; buf[1] dead -> reduction scratch.
  float lmin = 3.4e38f, lmax = -3.4e38f;
  float4* o0 = (float4*)(tout + m0 * IN_F);
  float4* o1 = (float4*)(tout + (m0 + 1) * IN_F);
#pragma unroll
  for (int j = 0; j < 4; j++) {
    int i4 = j * 256 + t;
    int c = i4 * 4;
    float4 q0 = *(float4*)&buf[0][c];
    float4 q1 = *(float4*)&buf[0][c + 2];
    o0[i4] = make_float4(q0.x, q0.z, q1.x, q1.z);
    o1[i4] = make_float4(q0.y, q0.w, q1.y, q1.w);
    lmin = fminf(lmin, fminf(fminf(q0.x, q0.y), fminf(q0.z, q0.w)));
    lmin = fminf(lmin, fminf(fminf(q1.x, q1.y), fminf(q1.z, q1.w)));
    lmax = fmaxf(lmax, fmaxf(fmaxf(q0.x, q0.y), fmaxf(q0.z, q0.w)));
    lmax = fmaxf(lmax, fmaxf(fmaxf(q1.x, q1.y), fmaxf(q1.z, q1.w)));
  }
#pragma unroll
  for (int off = 32; off > 0; off >>= 1) {
    lmin = fminf(lmin, __shfl_down(lmin, off));
    lmax = fmaxf(lmax, __shfl_down(lmax, off));
  }
  float* red = (float*)&buf[1][0];
  int wid = t >> 6;
  if ((t & 63) == 0) { red[wid * 2] = lmin; red[wid * 2 + 1] = lmax; }
  __syncthreads();
  if (t == 0) {
    float bmin = fminf(fminf(red[0], red[2]), fminf(red[4], red[6]));
    float bmax = fmaxf(fmaxf(red[1], red[3]), fmaxf(red[5], red[7]));
    atomicMin(&mm[mmidx], enc_f(bmin));
    atomicMax(&mm[mmidx + 1], enc_f(bmax));
  }
}

__global__ void finalize_kernel(unsigned* mm) {
  float* sc = (float*)(mm + 4);
  float xlo = dec_f(mm[0]), xhi = dec_f(mm[1]);
  float wlo = dec_f(mm[2]), whi = dec_f(mm[3]);
  float sx = (xhi - xlo) / 255.0f;
  float zx = rintf(-128.0f - xlo / sx);   // jnp.round == half-even == rintf
  float sw = (whi - wlo) / 255.0f;
  float zw = rintf(-128.0f - wlo / sw);
  sc[0] = sx; sc[1] = zx; sc[2] = sw; sc[3] = zw;
}

// quantize->dequantize one 4096-row into f16 at stride KTOT
__global__ __launch_bounds__(256) void quant_kernel(
    const float* __restrict__ src, f16* __restrict__ dst,
    const unsigned* __restrict__ mm, int scoff) {
  const float* sc = (const float*)(mm + 4);
  float s = sc[scoff], zp = sc[scoff + 1];
  int m = blockIdx.x, t = threadIdx.x;
  const float4* srow = (const float4*)(src + (size_t)m * IN_F);
  f16* drow = dst + (size_t)m * KTOT;
#pragma unroll
  for (int j = 0; j < 4; j++) {
    int i4 = j * 256 + t;
    float4 v = srow[i4];
    float q0 = (fminf(fmaxf(rintf(v.x / s + zp), -128.f), 127.f) - zp) * s;
    float q1 = (fminf(fmaxf(rintf(v.y / s + zp), -128.f), 127.f) - zp) * s;
    float q2 = (fminf(fmaxf(rintf(v.z / s + zp), -128.f), 127.f) - zp) * s;
    float q3 = (fminf(fmaxf(rintf(v.w / s + zp), -128.f), 127.f) - zp) * s;
    f16x4 o; o.x = (f16)q0; o.y = (f16)q1; o.z = (f16)q2; o.w = (f16)q3;
    *(f16x4*)(drow + i4 * 4) = o;
  }
}

// ---------------------------------------------------------------------------
// GEMM: out[8192,1024] = A_all[8192,12288] @ B_all[1024,12288]^T + bias
// 128x128 tile, 4 waves (2x2), each wave 4x4 of 16x16x32 f16 MFMA,
// global_load_lds width-16 staging. bm = blk&63 => XCD = bm%8: all 8 blocks
// sharing an A-tile sit on one XCD (A fetched once per XCD into its L2).
// ---------------------------------------------------------------------------
__device__ __forceinline__ void gl2lds16(const void* g, void* l) {
  __builtin_amdgcn_global_load_lds(
      (__attribute__((address_space(1))) void*)g,
      (__attribute__((address_space(3))) void*)l, 16, 0, 0);
}

__global__ __launch_bounds__(256, 2) void gemm_kernel(
    const f16* __restrict__ A, const f16* __restrict__ B,
    const float* __restrict__ bias, float* __restrict__ out) {
  __shared__ f16 As[128 * 32];
  __shared__ f16 Bs[128 * 32];
  const int tid = threadIdx.x;
  const int wave = tid >> 6, lane = tid & 63;
  const int quad = lane >> 4, fr = lane & 15;
  const int bm = blockIdx.x & 63, bn = blockIdx.x >> 6;   // XCD = bm % 8
  const int wm = (wave & 1) * 64, wn = (wave >> 1) * 64;

  f32x4 acc[4][4] = {};

  const int l4 = lane >> 2;          // row-within-16 covered by this lane
  const int lc = (lane & 3) * 8;     // f16 col offset (16B chunks)
  const size_t arow = (size_t)(bm * 128 + wave * 16 + l4);
  const size_t brow = (size_t)(bn * 128 + wave * 16 + l4);
  const f16* ag0 = A + arow * KTOT + lc;
  const f16* ag1 = A + (arow + 64) * KTOT + lc;
  const f16* bg0 = B + brow * KTOT + lc;
  const f16* bg1 = B + (brow + 64) * KTOT + lc;
  f16* as0 = As + (wave * 16) * 32;          // wave-uniform LDS bases
  f16* as1 = As + (64 + wave * 16) * 32;
  f16* bs0 = Bs + (wave * 16) * 32;
  f16* bs1 = Bs + (64 + wave * 16) * 32;

  for (int kk = 0; kk < KTOT; kk += 32) {
    gl2lds16(ag0 + kk, as0);
    gl2lds16(ag1 + kk, as1);
    gl2lds16(bg0 + kk, bs0);
    gl2lds16(bg1 + kk, bs1);
    __syncthreads();
    f16x8 af[4], bf[4];
#pragma unroll
    for (int mi = 0; mi < 4; mi++)
      af[mi] = *(const f16x8*)(As + (wm + mi * 16 + fr) * 32 + quad * 8);
#pragma unroll
    for (int ni = 0; ni < 4; ni++)
      bf[ni] = *(const f16x8*)(Bs + (wn + ni * 16 + fr) * 32 + quad * 8);
#pragma unroll
    for (int mi = 0; mi < 4; mi++)
#pragma unroll
      for (int ni = 0; ni < 4; ni++)
        acc[mi][ni] = __builtin_amdgcn_mfma_f32_16x16x32_f16(
            af[mi], bf[ni], acc[mi][ni], 0, 0, 0);
    __syncthreads();
  }

#pragma unroll
  for (int mi = 0; mi < 4; mi++) {
    int gm = bm * 128 + wm + mi * 16 + quad * 4;   // D row = quad*4+reg
#pragma unroll
    for (int ni = 0; ni < 4; ni++) {
      int gn = bn * 128 + wn + ni * 16 + fr;       // D col = lane&15
      float bv = bias[gn];
#pragma unroll
      for (int e = 0; e < 4; e++)
        out[(size_t)(gm + e) * OUT_F + gn] = acc[mi][ni][e] + bv;
    }
  }
}

// ---------------------------------------------------------------------------
extern "C" void kernel_launch(void* const* d_in, const int* in_sizes, int n_in,
                              void* d_out, int out_size, void* d_ws, size_t ws_size,
                              hipStream_t stream) {
  const float* x     = (const float*)d_in[0];
  const float* w     = (const float*)d_in[1];
  const float* bias  = (const float*)d_in[2];
  const float* wn    = (const float*)d_in[3];
  const float* nx    = (const float*)d_in[4];
  const int*   perms = (const int*)d_in[5];
  const float* mats  = (const float*)d_in[6];
  float* out = (float*)d_out;

  char* ws = (char*)d_ws;                       // needs ~379 MB
  float* xt   = (float*)(ws + OFF_XT);
  float* wt   = (float*)(ws + OFF_WT);
  f16*   Aall = (f16*)(ws + OFF_A);
  f16*   Ball = (f16*)(ws + OFF_B);
  unsigned* mm = (unsigned*)(ws + OFF_MM);
  int4*   tIx = (int4*)(ws + OFF_TIX);
  float4* tCx = (float4*)(ws + OFF_TCX);
  int4*   tIw = (int4*)(ws + OFF_TIW);
  float4* tCw = (float4*)(ws + OFF_TCW);

  init_mm_kernel<<<1, 1, 0, stream>>>(mm);
  build_tables_kernel<<<NPASS, 256, 0, stream>>>(perms, mats, tIx, tCx, tIw, tCw);
  transform_kernel<false><<<MROWS / 2, 256, 0, stream>>>(x, nx, tIx, tCx, xt, Aall, mm, 0);
  transform_kernel<true><<<OUT_F / 2, 256, 0, stream>>>(w, wn, tIw, tCw, wt, Ball, mm, 2);
  finalize_kernel<<<1, 1, 0, stream>>>(mm);
  quant_kernel<<<MROWS, 256, 0, stream>>>(xt, Aall, mm, 0);
  quant_kernel<<<OUT_F, 256, 0, stream>>>(wt, Ball, mm, 2);
  gemm_kernel<<<(MROWS / 128) * (OUT_F / 128), 256, 0, stream>>>(Aall, Ball, bias, out);
}

// Round 3
// 736.087 us; speedup vs baseline: 1.1163x; 1.0263x over previous
//
#include <hip/hip_runtime.h>

// ---------------------------------------------------------------------------
// QuantizedPermutationNoiseLinear  (B=4, S=2048, IN=4096, OUT=1024, ROUNDS=12)
//
// res = QDQ(T(x+nx)) @ QDQ(Tw(w+wn)).T + bias - x@wn.T - nx@(w+wn).T
//
// R3 changes vs R2 (both hot kernels were occupancy/latency-bound):
//  - GEMM split-K=2 -> 1024 blocks (4 blocks/CU, was 2); bias pre-init kernel
//    + unsafeAtomicAdd f32 epilogue. XCD invariant blk%8==bm%8 preserved.
//  - Transform: 1024 threads/block (32 waves/CU, was 8), x+w rows merged into
//    one launch, u16-packed gather indices. f32 coefs kept (f16 coefs would
//    flip quant buckets -> absmax blowup).
// ---------------------------------------------------------------------------

#define IN_F   4096
#define OUT_F  1024
#define MROWS  8192          // B*S
#define KTOT   12288
#define KHALF  6144
#define NPASS  6             // merged rounds (12 -> 6)

typedef _Float16 f16;
typedef _Float16 f16x8 __attribute__((ext_vector_type(8)));
typedef _Float16 f16x4 __attribute__((ext_vector_type(4)));
typedef float    f32x4 __attribute__((ext_vector_type(4)));

// ---- workspace layout (bytes) --- total ~379 MB ---------------------------
#define OFF_XT  (0ull)                                   // 8192*4096*4 = 128 MB
#define OFF_WT  (OFF_XT + (size_t)MROWS * IN_F * 4)      // 1024*4096*4 = 16 MB
#define OFF_A   (OFF_WT + (size_t)OUT_F * IN_F * 4)      // 8192*12288*2 = 192 MB
#define OFF_B   (OFF_A + (size_t)MROWS * KTOT * 2)       // 1024*12288*2 = 24 MB
#define OFF_MM  (OFF_B + (size_t)OUT_F * KTOT * 2)       // 4 u32 + 4 f32
#define OFF_TIX (OFF_MM + 256)                           // 6*2048*8  = 96 KB
#define OFF_TCX (OFF_TIX + (size_t)NPASS * 2048 * 8)     // 6*2048*32 = 384 KB
#define OFF_TIW (OFF_TCX + (size_t)NPASS * 2048 * 32)
#define OFF_TCW (OFF_TIW + (size_t)NPASS * 2048 * 8)

// ---- sortable-uint encoding for float atomic min/max ----------------------
__device__ __forceinline__ unsigned enc_f(float f) {
  unsigned u = __float_as_uint(f);
  return (u & 0x80000000u) ? ~u : (u | 0x80000000u);
}
__device__ __forceinline__ float dec_f(unsigned u) {
  unsigned b = (u & 0x80000000u) ? (u & 0x7fffffffu) : ~u;
  return __uint_as_float(b);
}

// ---------------------------------------------------------------------------
// Build merged-round tables (pass p composes rounds 2p, 2p+1). Also inits mm.
// idx packed as u16x4 in uint2.
// ---------------------------------------------------------------------------
__global__ void build_tables_kernel(const int* __restrict__ perms,
                                    const float* __restrict__ mats,
                                    uint2* __restrict__ tIx, float4* __restrict__ tCx,
                                    uint2* __restrict__ tIw, float4* __restrict__ tCw,
                                    unsigned* __restrict__ mm) {
  if (blockIdx.x == 0 && threadIdx.x == 0) {
    mm[0] = 0xFFFFFFFFu; mm[1] = 0u; mm[2] = 0xFFFFFFFFu; mm[3] = 0u;
  }
  int p = blockIdx.x;  // 0..5
  int r0 = 2 * p, r1 = 2 * p + 1;
  for (int g = threadIdx.x; g < 2048; g += blockDim.x) {
    int q0 = perms[r1 * IN_F + 2 * g], q1 = perms[r1 * IN_F + 2 * g + 1];
    int a0 = q0 >> 1, e0 = q0 & 1, a1 = q1 >> 1, e1 = q1 & 1;
    unsigned i0 = perms[r0 * IN_F + 2 * a0], i1 = perms[r0 * IN_F + 2 * a0 + 1];
    unsigned i2 = perms[r0 * IN_F + 2 * a1], i3 = perms[r0 * IN_F + 2 * a1 + 1];
    uint2 idx = make_uint2(i0 | (i1 << 16), i2 | (i3 << 16));
    const float* Ma = mats + ((size_t)r0 * 2048 + a0) * 4;  // [a,b,c,d]
    const float* Mb = mats + ((size_t)r0 * 2048 + a1) * 4;
    const float* M1 = mats + ((size_t)r1 * 2048 + g) * 4;
    int o = p * 2048 + g;
    { // forward
      float c00 = Ma[e0 * 2], c01 = Ma[e0 * 2 + 1];
      float c10 = Mb[e1 * 2], c11 = Mb[e1 * 2 + 1];
      float m00 = M1[0], m01 = M1[1], m10 = M1[2], m11 = M1[3];
      tIx[o] = idx;
      tCx[2 * o]     = make_float4(m00 * c00, m00 * c01, m01 * c10, m01 * c11);
      tCx[2 * o + 1] = make_float4(m10 * c00, m10 * c01, m11 * c10, m11 * c11);
    }
    { // inverse-transpose (weight): N = [[d,-c],[-b,a]]/det
      float rda = 1.0f / (Ma[0] * Ma[3] - Ma[1] * Ma[2]);
      float rdb = 1.0f / (Mb[0] * Mb[3] - Mb[1] * Mb[2]);
      float rd1 = 1.0f / (M1[0] * M1[3] - M1[1] * M1[2]);
      float c00 = (e0 == 0 ? Ma[3] : -Ma[1]) * rda;
      float c01 = (e0 == 0 ? -Ma[2] : Ma[0]) * rda;
      float c10 = (e1 == 0 ? Mb[3] : -Mb[1]) * rdb;
      float c11 = (e1 == 0 ? -Mb[2] : Mb[0]) * rdb;
      float m00 = M1[3] * rd1, m01 = -M1[2] * rd1;
      float m10 = -M1[1] * rd1, m11 = M1[0] * rd1;
      tIw[o] = idx;
      tCw[2 * o]     = make_float4(m00 * c00, m00 * c01, m01 * c10, m01 * c11);
      tCw[2 * o + 1] = make_float4(m10 * c00, m10 * c01, m11 * c10, m11 * c11);
    }
  }
}

// ---------------------------------------------------------------------------
// Transform: 1024 threads, 2 rows/block (float2-packed), 6 merged LDS passes.
// Grid = 4096 x-blocks then 512 w-blocks (one launch).
//  x path: f16out rows [.. | -x | -nx] (A_all);  w path: [.. | wn | w+wn].
// ---------------------------------------------------------------------------
__global__ __launch_bounds__(1024) void transform_kernel(
    const float* __restrict__ x, const float* __restrict__ nx,
    const float* __restrict__ w, const float* __restrict__ wn,
    const uint2* __restrict__ tIx, const float4* __restrict__ tCx,
    const uint2* __restrict__ tIw, const float4* __restrict__ tCw,
    float* __restrict__ xt, float* __restrict__ wt,
    f16* __restrict__ Aall, f16* __restrict__ Ball,
    unsigned* __restrict__ mm) {
  __shared__ float2 buf[2][IN_F];   // 64 KB
  const int t = threadIdx.x;
  const bool isW = blockIdx.x >= (MROWS / 2);
  const float *in0, *in1; const uint2* tI; const float4* tC;
  float* tout; f16* fout; int mmidx; size_t m0;
  if (!isW) {
    m0 = (size_t)blockIdx.x * 2;
    in0 = x; in1 = nx; tI = tIx; tC = tCx; tout = xt; fout = Aall; mmidx = 0;
  } else {
    m0 = (size_t)(blockIdx.x - MROWS / 2) * 2;
    in0 = w; in1 = wn; tI = tIw; tC = tCw; tout = wt; fout = Ball; mmidx = 2;
  }
  f16* f0 = fout + m0 * KTOT;
  f16* f1 = fout + (m0 + 1) * KTOT;

  {
    float4 a0 = ((const float4*)(in0 + m0 * IN_F))[t];
    float4 b0 = ((const float4*)(in1 + m0 * IN_F))[t];
    float4 a1 = ((const float4*)(in0 + (m0 + 1) * IN_F))[t];
    float4 b1 = ((const float4*)(in1 + (m0 + 1) * IN_F))[t];
    float4 s0 = make_float4(a0.x + b0.x, a0.y + b0.y, a0.z + b0.z, a0.w + b0.w);
    float4 s1 = make_float4(a1.x + b1.x, a1.y + b1.y, a1.z + b1.z, a1.w + b1.w);
    int c = t * 4;
    *(float4*)&buf[0][c]     = make_float4(s0.x, s1.x, s0.y, s1.y);
    *(float4*)&buf[0][c + 2] = make_float4(s0.z, s1.z, s0.w, s1.w);
    f16x4 p0, p1, q0, q1;
    if (isW) {
      p0.x=(f16)b0.x; p0.y=(f16)b0.y; p0.z=(f16)b0.z; p0.w=(f16)b0.w;   // wn
      q0.x=(f16)s0.x; q0.y=(f16)s0.y; q0.z=(f16)s0.z; q0.w=(f16)s0.w;   // w+wn
      p1.x=(f16)b1.x; p1.y=(f16)b1.y; p1.z=(f16)b1.z; p1.w=(f16)b1.w;
      q1.x=(f16)s1.x; q1.y=(f16)s1.y; q1.z=(f16)s1.z; q1.w=(f16)s1.w;
    } else {
      p0.x=(f16)(-a0.x); p0.y=(f16)(-a0.y); p0.z=(f16)(-a0.z); p0.w=(f16)(-a0.w); // -x
      q0.x=(f16)(-b0.x); q0.y=(f16)(-b0.y); q0.z=(f16)(-b0.z); q0.w=(f16)(-b0.w); // -nx
      p1.x=(f16)(-a1.x); p1.y=(f16)(-a1.y); p1.z=(f16)(-a1.z); p1.w=(f16)(-a1.w);
      q1.x=(f16)(-b1.x); q1.y=(f16)(-b1.y); q1.z=(f16)(-b1.z); q1.w=(f16)(-b1.w);
    }
    *(f16x4*)(f0 + IN_F + c)     = p0;
    *(f16x4*)(f0 + 2 * IN_F + c) = q0;
    *(f16x4*)(f1 + IN_F + c)     = p1;
    *(f16x4*)(f1 + 2 * IN_F + c) = q1;
  }
  __syncthreads();

  int cur = 0;
  for (int pass = 0; pass < NPASS; pass++) {
    const uint2* ti = tI + pass * 2048;
    const float4* tc = tC + (size_t)pass * 4096;
#pragma unroll
    for (int i = 0; i < 2; i++) {
      int g = i * 1024 + t;             // output pair index 0..2047
      uint2 pk = ti[g];
      float4 cA = tc[2 * g], cB = tc[2 * g + 1];
      float2 x0 = buf[cur][pk.x & 0xffff], x1 = buf[cur][pk.x >> 16];
      float2 x2 = buf[cur][pk.y & 0xffff], x3 = buf[cur][pk.y >> 16];
      float y0x = cA.x * x0.x + cA.y * x1.x + cA.z * x2.x + cA.w * x3.x;
      float y0y = cA.x * x0.y + cA.y * x1.y + cA.z * x2.y + cA.w * x3.y;
      float y1x = cB.x * x0.x + cB.y * x1.x + cB.z * x2.x + cB.w * x3.x;
      float y1y = cB.x * x0.y + cB.y * x1.y + cB.z * x2.y + cB.w * x3.y;
      *(float4*)&buf[cur ^ 1][2 * g] = make_float4(y0x, y0y, y1x, y1y);
    }
    cur ^= 1;
    __syncthreads();
  }
  // result in buf[0]; buf[1] dead -> reduction scratch.
  float lmin = 3.4e38f, lmax = -3.4e38f;
  {
    int c = t * 4;
    float4 q0 = *(float4*)&buf[0][c];
    float4 q1 = *(float4*)&buf[0][c + 2];
    ((float4*)(tout + m0 * IN_F))[t]       = make_float4(q0.x, q0.z, q1.x, q1.z);
    ((float4*)(tout + (m0 + 1) * IN_F))[t] = make_float4(q0.y, q0.w, q1.y, q1.w);
    lmin = fminf(fminf(fminf(q0.x, q0.y), fminf(q0.z, q0.w)),
                 fminf(fminf(q1.x, q1.y), fminf(q1.z, q1.w)));
    lmax = fmaxf(fmaxf(fmaxf(q0.x, q0.y), fmaxf(q0.z, q0.w)),
                 fmaxf(fmaxf(q1.x, q1.y), fmaxf(q1.z, q1.w)));
  }
#pragma unroll
  for (int off = 32; off > 0; off >>= 1) {
    lmin = fminf(lmin, __shfl_down(lmin, off));
    lmax = fmaxf(lmax, __shfl_down(lmax, off));
  }
  float* red = (float*)&buf[1][0];
  int wid = t >> 6;
  if ((t & 63) == 0) { red[wid * 2] = lmin; red[wid * 2 + 1] = lmax; }
  __syncthreads();
  if (t == 0) {
    float bmin = red[0], bmax = red[1];
#pragma unroll
    for (int i = 1; i < 16; i++) {
      bmin = fminf(bmin, red[i * 2]);
      bmax = fmaxf(bmax, red[i * 2 + 1]);
    }
    atomicMin(&mm[mmidx], enc_f(bmin));
    atomicMax(&mm[mmidx + 1], enc_f(bmax));
  }
}

__global__ void finalize_kernel(unsigned* mm) {
  float* sc = (float*)(mm + 4);
  float xlo = dec_f(mm[0]), xhi = dec_f(mm[1]);
  float wlo = dec_f(mm[2]), whi = dec_f(mm[3]);
  float sx = (xhi - xlo) / 255.0f;
  float zx = rintf(-128.0f - xlo / sx);   // jnp.round == half-even == rintf
  float sw = (whi - wlo) / 255.0f;
  float zw = rintf(-128.0f - wlo / sw);
  sc[0] = sx; sc[1] = zx; sc[2] = sw; sc[3] = zw;
}

// quantize->dequantize rows into f16 at stride KTOT; x rows then w rows.
__global__ __launch_bounds__(256) void quant_kernel(
    const float* __restrict__ xt, const float* __restrict__ wt,
    f16* __restrict__ Aall, f16* __restrict__ Ball,
    const unsigned* __restrict__ mm) {
  const float* sc = (const float*)(mm + 4);
  const bool isW = blockIdx.x >= MROWS;
  int m = isW ? blockIdx.x - MROWS : blockIdx.x;
  float s = isW ? sc[2] : sc[0], zp = isW ? sc[3] : sc[1];
  const float4* srow = (const float4*)((isW ? wt : xt) + (size_t)m * IN_F);
  f16* drow = (isW ? Ball : Aall) + (size_t)m * KTOT;
  int t = threadIdx.x;
#pragma unroll
  for (int j = 0; j < 4; j++) {
    int i4 = j * 256 + t;
    float4 v = srow[i4];
    float q0 = (fminf(fmaxf(rintf(v.x / s + zp), -128.f), 127.f) - zp) * s;
    float q1 = (fminf(fmaxf(rintf(v.y / s + zp), -128.f), 127.f) - zp) * s;
    float q2 = (fminf(fmaxf(rintf(v.z / s + zp), -128.f), 127.f) - zp) * s;
    float q3 = (fminf(fmaxf(rintf(v.w / s + zp), -128.f), 127.f) - zp) * s;
    f16x4 o; o.x = (f16)q0; o.y = (f16)q1; o.z = (f16)q2; o.w = (f16)q3;
    *(f16x4*)(drow + i4 * 4) = o;
  }
}

// out[m, n] = bias[n]  (pre-init for atomic GEMM epilogue)
__global__ __launch_bounds__(256) void bias_init_kernel(
    const float* __restrict__ bias, float* __restrict__ out) {
  const float4* b4 = (const float4*)bias;
  float4* o4 = (float4*)out;
  int idx = blockIdx.x * 256 + threadIdx.x;        // grid covers 2.1M float4
  const int total = MROWS * OUT_F / 4;
  for (int i = idx; i < total; i += gridDim.x * 256)
    o4[i] = b4[i & (OUT_F / 4 - 1)];
}

// ---------------------------------------------------------------------------
// GEMM: out += A_all[8192,12288] @ B_all[1024,12288]^T   (split-K = 2)
// 128x128 tile, 4 waves (2x2), 4x4 of 16x16x32 f16 MFMA, global_load_lds
// width-16. blk = s*512 + bn*64 + bm  =>  XCD = blk%8 = bm%8 (A stays in
// one XCD's L2). Epilogue: HW f32 atomic add (bias pre-initialized).
// ---------------------------------------------------------------------------
__device__ __forceinline__ void gl2lds16(const void* g, void* l) {
  __builtin_amdgcn_global_load_lds(
      (__attribute__((address_space(1))) void*)g,
      (__attribute__((address_space(3))) void*)l, 16, 0, 0);
}

__global__ __launch_bounds__(256, 4) void gemm_kernel(
    const f16* __restrict__ A, const f16* __restrict__ B,
    float* __restrict__ out) {
  __shared__ f16 As[128 * 32];
  __shared__ f16 Bs[128 * 32];
  const int tid = threadIdx.x;
  const int wave = tid >> 6, lane = tid & 63;
  const int quad = lane >> 4, fr = lane & 15;
  const int bm = blockIdx.x & 63;
  const int bn = (blockIdx.x >> 6) & 7;
  const int ks = blockIdx.x >> 9;                 // split index 0/1
  const int k0 = ks * KHALF;
  const int wm = (wave & 1) * 64, wn = (wave >> 1) * 64;

  f32x4 acc[4][4] = {};

  const int l4 = lane >> 2;
  const int lc = (lane & 3) * 8;
  const size_t arow = (size_t)(bm * 128 + wave * 16 + l4);
  const size_t brow = (size_t)(bn * 128 + wave * 16 + l4);
  const f16* ag0 = A + arow * KTOT + k0 + lc;
  const f16* ag1 = A + (arow + 64) * KTOT + k0 + lc;
  const f16* bg0 = B + brow * KTOT + k0 + lc;
  const f16* bg1 = B + (brow + 64) * KTOT + k0 + lc;
  f16* as0 = As + (wave * 16) * 32;
  f16* as1 = As + (64 + wave * 16) * 32;
  f16* bs0 = Bs + (wave * 16) * 32;
  f16* bs1 = Bs + (64 + wave * 16) * 32;

  for (int kk = 0; kk < KHALF; kk += 32) {
    gl2lds16(ag0 + kk, as0);
    gl2lds16(ag1 + kk, as1);
    gl2lds16(bg0 + kk, bs0);
    gl2lds16(bg1 + kk, bs1);
    __syncthreads();
    f16x8 af[4], bf[4];
#pragma unroll
    for (int mi = 0; mi < 4; mi++)
      af[mi] = *(const f16x8*)(As + (wm + mi * 16 + fr) * 32 + quad * 8);
#pragma unroll
    for (int ni = 0; ni < 4; ni++)
      bf[ni] = *(const f16x8*)(Bs + (wn + ni * 16 + fr) * 32 + quad * 8);
#pragma unroll
    for (int mi = 0; mi < 4; mi++)
#pragma unroll
      for (int ni = 0; ni < 4; ni++)
        acc[mi][ni] = __builtin_amdgcn_mfma_f32_16x16x32_f16(
            af[mi], bf[ni], acc[mi][ni], 0, 0, 0);
    __syncthreads();
  }

#pragma unroll
  for (int mi = 0; mi < 4; mi++) {
    int gm = bm * 128 + wm + mi * 16 + quad * 4;   // D row = quad*4+reg
#pragma unroll
    for (int ni = 0; ni < 4; ni++) {
      int gn = bn * 128 + wn + ni * 16 + fr;       // D col = lane&15
#pragma unroll
      for (int e = 0; e < 4; e++)
        unsafeAtomicAdd(&out[(size_t)(gm + e) * OUT_F + gn], acc[mi][ni][e]);
    }
  }
}

// ---------------------------------------------------------------------------
extern "C" void kernel_launch(void* const* d_in, const int* in_sizes, int n_in,
                              void* d_out, int out_size, void* d_ws, size_t ws_size,
                              hipStream_t stream) {
  const float* x     = (const float*)d_in[0];
  const float* w     = (const float*)d_in[1];
  const float* bias  = (const float*)d_in[2];
  const float* wn    = (const float*)d_in[3];
  const float* nx    = (const float*)d_in[4];
  const int*   perms = (const int*)d_in[5];
  const float* mats  = (const float*)d_in[6];
  float* out = (float*)d_out;

  char* ws = (char*)d_ws;                       // needs ~379 MB
  float* xt   = (float*)(ws + OFF_XT);
  float* wt   = (float*)(ws + OFF_WT);
  f16*   Aall = (f16*)(ws + OFF_A);
  f16*   Ball = (f16*)(ws + OFF_B);
  unsigned* mm = (unsigned*)(ws + OFF_MM);
  uint2*  tIx = (uint2*)(ws + OFF_TIX);
  float4* tCx = (float4*)(ws + OFF_TCX);
  uint2*  tIw = (uint2*)(ws + OFF_TIW);
  float4* tCw = (float4*)(ws + OFF_TCW);

  build_tables_kernel<<<NPASS, 256, 0, stream>>>(perms, mats, tIx, tCx, tIw, tCw, mm);
  transform_kernel<<<MROWS / 2 + OUT_F / 2, 1024, 0, stream>>>(
      x, nx, w, wn, tIx, tCx, tIw, tCw, xt, wt, Aall, Ball, mm);
  finalize_kernel<<<1, 1, 0, stream>>>(mm);
  quant_kernel<<<MROWS + OUT_F, 256, 0, stream>>>(xt, wt, Aall, Ball, mm);
  bias_init_kernel<<<1024, 256, 0, stream>>>(bias, out);
  gemm_kernel<<<2 * (MROWS / 128) * (OUT_F / 128), 256, 0, stream>>>(Aall, Ball, out);
}